// Round 18
// baseline (100.355 us; speedup 1.0000x reference)
//
#include <hip/hip_runtime.h>

// Problem constants (fixed by setup_inputs).
#define B_     16
#define C_     3
#define H_     512
#define W_     1024
#define MW     256         // mask_width
#define RS     16          // output rows per strip
#define NSTRIP 32          // 32*16 = 512 exact (no ragged strip)
#define NIN    (RS + 10)   // 26 input rows streamed per strip
#define NBLK   (B_ * C_ * NSTRIP)  // 1536

// Memory fence only: wave_barrier pins all DS/VMEM ordering (IR + MIR) but
// lets pure VALU flow across iterations (software pipelining).
#define FENCE() __builtin_amdgcn_wave_barrier()

// Packed-FP32 pair type: (u-field, v-field) computed with one v_pk_* each.
typedef float f2 __attribute__((ext_vector_type(2)));

__global__ __launch_bounds__(256) void ssim_main(const float* __restrict__ img1,
                                                 const float* __restrict__ img2,
                                                 const int*   __restrict__ mask_pos,
                                                 float*       __restrict__ partials) {
    // Gaussian weights = float64 exp/normalize, precomputed to float literals.
    constexpr float G[11] = {
        0.00102838f, 0.00759876f, 0.03600077f, 0.10936070f, 0.21300553f,
        0.26601173f, 0.21300553f, 0.10936070f, 0.03600077f, 0.00759876f,
        0.00102838f };

    // Per-wave double-buffered 74-col {u=x+y, v=x-y} row ring. ~5 KB total.
    __shared__ f2    rowbuf[4][2][80];
    __shared__ float blksum[4];

    const int tid  = threadIdx.x;
    const int w    = tid >> 6;
    const int lane = tid & 63;

    // L2-locality remap: 8 XCDs x 6 images x 32 strips (bijection, 1536).
    const int d     = blockIdx.x;
    const int xcd   = d & 7;
    const int q     = d >> 3;            // 0..191 within XCD
    const int bc    = xcd * 6 + (q >> 5);// (b,ch) 0..47
    const int strip = q & 31;            // row strip 0..31
    const int b     = bc / 3;

    int s0 = mask_pos[b];
    s0 = min(max(s0, 0), W_ - MW);

    const float* __restrict__ p1 = img1 + (size_t)bc * (H_ * W_);
    const float* __restrict__ p2 = img2 + (size_t)bc * (H_ * W_);

    const int y0  = strip * RS;
    const int sx0 = w << 6;              // column strip base within crop
    const int cxm = sx0 - 5 + lane;      // main staged column (crop coords)
    const int cxh = sx0 + 59 + lane;     // halo staged column (lane < 10)
    const bool vm = (cxm >= 0) && (cxm < MW);
    const bool vh = (lane < 10) && (cxh < MW);
    const int gxm = s0 + cxm;
    const int gxh = s0 + cxh;

    // Single in-flight prefetch register set (distance 1) — RAW values only.
    // u/v transform happens AT THE STORE (bottom of iteration) so the vmcnt
    // wait stays at the ds_write, hidden under this row's compute.
    float pa0, pb0, pa1, pb1;
    auto loadrow = [&](int r) {
        pa0 = pb0 = pa1 = pb1 = 0.f;
        if (r >= 0 && r < H_) {          // wave-uniform branch
            const int ro = r * W_;
            if (vm) { pa0 = p1[ro + gxm]; pb0 = p2[ro + gxm]; }
            if (vh) { pa1 = p1[ro + gxh]; pb1 = p2[ro + gxh]; }
        }
    };

    // 11 pending output rows: accm = (mu_p, mu_m), accs = (Suu, Svv) as
    // packed pairs. Same 44-float footprint as round 16; slot index `sl` is
    // compile-time at every call site. SCATTER-RMW form is load-bearing for
    // regalloc (gather form spilled, round 13).
    f2 accm[11], accs[11];
    #pragma unroll
    for (int s = 0; s < 11; ++s) { accm[s] = (f2){0.f, 0.f}; accs[s] = (f2){0.f, 0.f}; }

    float psum = 0.f;
    int cur = 0;                         // runtime LDS parity (LDS, not VGPR array)

    auto dorow = [&](int i, int sl) {
        const bool notlast = (i + 1 < NIN);

        // Prefetch row i+1 into registers (hidden under this row's math).
        if (notlast) loadrow(y0 - 4 + i);

        // Horizontal 11-tap pass, PACKED over the (u,v) pair: one v_pk_mul /
        // v_pk_add / v_pk_fma per tap-field instead of two scalar ops.
        f2 susv   = (f2){0.f, 0.f};
        f2 suusvv = (f2){0.f, 0.f};
        #pragma unroll
        for (int t = 0; t < 11; ++t) {
            const f2 q2 = rowbuf[w][cur][lane + t];
            const f2 g2 = G[t] * q2;             // v_pk_mul_f32
            susv   += g2;                        // v_pk_add_f32
            suusvv  = g2 * q2 + suusvv;          // contracts to v_pk_fma_f32
        }

        // Vertical accumulation, packed: 22 pk_fma instead of 44 fma.
        #pragma unroll
        for (int m = 0; m < 11; ++m) {
            const int s = (sl + m) % 11;
            const float gw = G[10 - m];
            accm[s] = gw * susv   + accm[s];     // v_pk_fma_f32
            accs[s] = gw * suusvv + accs[s];     // v_pk_fma_f32
        }

        // Output row o = y0 + i - 10 completes in slot sl at i >= 10.
        if (i >= 10) {
            const float mup = accm[sl].x, mum = accm[sl].y;
            const float Suu = accs[sl].x, Svv = accs[sl].y;
            const float A  = mup * mup, Bq = mum * mum;
            const float mu_sq_sum = 0.5f * (A + Bq);    // mu1^2 + mu2^2
            const float mu_cross2 = 0.5f * (A - Bq);    // 2*mu1*mu2
            const float e_sum     = 0.5f * (Suu + Svv); // Exx + Eyy
            const float e_cross2  = 0.5f * (Suu - Svv); // 2*Exy
            const float sig_sum = e_sum - mu_sq_sum;    // sig1 + sig2
            const float sig12_2 = e_cross2 - mu_cross2; // 2*sig12
            const float num = (mu_cross2 + 1e-4f) * (sig12_2 + 9e-4f) + 1e-5f;
            const float den = (mu_sq_sum + 1e-4f) * (sig_sum + 9e-4f) + 1e-5f;
            psum += __fdividef(num, den);
        }
        // Slot sl recycled: always reset.
        accm[sl] = (f2){0.f, 0.f};
        accs[sl] = (f2){0.f, 0.f};

        // Stage prefetched row i+1: u/v computed INLINE at the store, so the
        // first use of the loads (and the vmcnt wait) is here.
        if (notlast) {
            rowbuf[w][cur ^ 1][lane] = (f2){pa0 + pb0, pa0 - pb0};
            if (lane < 10)
                rowbuf[w][cur ^ 1][64 + lane] = (f2){pa1 + pb1, pa1 - pb1};
        }
        cur ^= 1;
        // Memory-only fence: DS/VMEM may not cross; VALU may.
        FENCE();
    };

    // Prologue: stage streamed row 0 (input row y0-5) into parity 0.
    loadrow(y0 - 5);
    rowbuf[w][0][lane] = (f2){pa0 + pb0, pa0 - pb0};
    if (lane < 10) rowbuf[w][0][64 + lane] = (f2){pa1 + pb1, pa1 - pb1};
    FENCE();

    // Main 22 rows (2 x 11 so sl stays compile-time; >11-deep fenced unrolls
    // spill — rounds 4/6/12), then 4-row tail (22 % 11 == 0 -> slot == j).
    for (int ii = 0; ii < 22; ii += 11) {
        #pragma unroll
        for (int j = 0; j < 11; ++j) dorow(ii + j, j);
    }
    #pragma unroll
    for (int j = 0; j < 4; ++j) dorow(22 + j, j);

    // Wave reduce -> block reduce -> one plain store per block (no atomic,
    // no zeroing: every slot written every run).
    #pragma unroll
    for (int off = 32; off > 0; off >>= 1) psum += __shfl_xor(psum, off, 64);
    if (lane == 0) blksum[w] = psum;
    __syncthreads();
    if (tid == 0) {
        partials[d] = blksum[0] + blksum[1] + blksum[2] + blksum[3];
    }
}

__global__ __launch_bounds__(256) void ssim_final(const float* __restrict__ partials,
                                                  float* __restrict__ out) {
    __shared__ float red[4];
    const int t = threadIdx.x;
    float s = 0.f;
    #pragma unroll
    for (int k = 0; k < NBLK / 256; ++k) s += partials[t + 256 * k];
    #pragma unroll
    for (int off = 32; off > 0; off >>= 1) s += __shfl_xor(s, off, 64);
    if ((t & 63) == 0) red[t >> 6] = s;
    __syncthreads();
    if (t == 0)
        out[0] = 1.0f - (red[0] + red[1] + red[2] + red[3]) * (1.0f / 6291456.0f);
}

extern "C" void kernel_launch(void* const* d_in, const int* in_sizes, int n_in,
                              void* d_out, int out_size, void* d_ws, size_t ws_size,
                              hipStream_t stream) {
    const float* img1 = (const float*)d_in[0];
    const float* img2 = (const float*)d_in[1];
    const int*   pos  = (const int*)d_in[2];
    float* out      = (float*)d_out;
    float* partials = (float*)d_ws;      // NBLK floats = 6 KB scratch

    // No memset: every partials slot is unconditionally written by ssim_main.
    // 8 XCDs x 6 images x 32 strips; each block = 4 waves = 4 column strips.
    ssim_main<<<NBLK, 256, 0, stream>>>(img1, img2, pos, partials);
    ssim_final<<<1, 256, 0, stream>>>(partials, out);
}

// Round 19
// 38.888 us; speedup vs baseline: 2.5806x; 2.5806x over previous
//
#include <hip/hip_runtime.h>

// Problem constants (fixed by setup_inputs).
#define B_     16
#define C_     3
#define H_     512
#define W_     1024
#define MW     256         // mask_width
#define RS     16          // output rows per strip
#define NSTRIP 32          // 32*16 = 512 exact (no ragged strip)
#define NIN    (RS + 10)   // 26 input rows streamed per strip
#define NBLK   (B_ * C_ * NSTRIP)  // 1536

// Memory fence only: wave_barrier pins all DS/VMEM ordering (IR + MIR) but
// lets pure VALU flow across iterations (software pipelining).
#define FENCE() __builtin_amdgcn_wave_barrier()

__global__ __launch_bounds__(256) void ssim_main(const float* __restrict__ img1,
                                                 const float* __restrict__ img2,
                                                 const int*   __restrict__ mask_pos,
                                                 float*       __restrict__ partials) {
    // Gaussian weights = float64 exp/normalize, precomputed to float literals.
    constexpr float G[11] = {
        0.00102838f, 0.00759876f, 0.03600077f, 0.10936070f, 0.21300553f,
        0.26601173f, 0.21300553f, 0.10936070f, 0.03600077f, 0.00759876f,
        0.00102838f };

    // Per-wave double-buffered 74-col {u=x+y, v=x-y} row ring. ~5 KB total.
    __shared__ float2 rowbuf[4][2][80];
    __shared__ float  blksum[4];

    const int tid  = threadIdx.x;
    const int w    = tid >> 6;
    const int lane = tid & 63;

    // L2-locality remap: dispatch round-robins blockIdx over the 8 XCDs, so
    // give each XCD 6 complete (b,ch) images with sequential strips. Adjacent
    // strips (which share 10 halo rows) then hit the same XCD's L2.
    // Bijection: 1536 = 8 xcd * (6 images * 32 strips).
    const int d     = blockIdx.x;
    const int xcd   = d & 7;
    const int q     = d >> 3;            // 0..191 within XCD
    const int bc    = xcd * 6 + (q >> 5);// (b,ch) 0..47
    const int strip = q & 31;            // row strip 0..31
    const int b     = bc / 3;

    int s0 = mask_pos[b];
    s0 = min(max(s0, 0), W_ - MW);

    const float* __restrict__ p1 = img1 + (size_t)bc * (H_ * W_);
    const float* __restrict__ p2 = img2 + (size_t)bc * (H_ * W_);

    const int y0  = strip * RS;
    const int sx0 = w << 6;              // column strip base within crop
    const int cxm = sx0 - 5 + lane;      // main staged column (crop coords)
    const int cxh = sx0 + 59 + lane;     // halo staged column (lane < 10)
    const bool vm = (cxm >= 0) && (cxm < MW);
    const bool vh = (lane < 10) && (cxh < MW);
    const int gxm = s0 + cxm;
    const int gxh = s0 + cxh;

    // Single in-flight prefetch register set (distance 1) — RAW values only.
    // u/v transform happens AT THE STORE (bottom of iteration) so the vmcnt
    // wait stays at the ds_write, hidden under this row's compute.
    float pa0, pb0, pa1, pb1;
    auto loadrow = [&](int r) {
        pa0 = pb0 = pa1 = pb1 = 0.f;
        if (r >= 0 && r < H_) {          // wave-uniform branch
            const int ro = r * W_;
            if (vm) { pa0 = p1[ro + gxm]; pb0 = p2[ro + gxm]; }
            if (vh) { pa1 = p1[ro + gxh]; pb1 = p2[ro + gxh]; }
        }
    };

    // 11 pending output rows x 4 conv fields {mu_p, mu_m, Suu, Svv};
    // slot index `sl` is compile-time at every call site. SCATTER-RMW form
    // is load-bearing for regalloc (gather form spilled, round 13).
    float acc[11][4];
    #pragma unroll
    for (int s = 0; s < 11; ++s)
        #pragma unroll
        for (int f = 0; f < 4; ++f) acc[s][f] = 0.f;

    float psum = 0.f;
    int cur = 0;                         // runtime LDS parity (LDS, not VGPR array)

    auto dorow = [&](int i, int sl) {
        const bool notlast = (i + 1 < NIN);

        // Prefetch row i+1 into registers (hidden under this row's math).
        if (notlast) loadrow(y0 - 4 + i);

        // Horizontal 11-tap pass over 4 fields from LDS buffer `cur`.
        float su = 0.f, sv = 0.f, suu = 0.f, svv = 0.f;
        #pragma unroll
        for (int t = 0; t < 11; ++t) {
            const float2 q2 = rowbuf[w][cur][lane + t];
            const float gu = G[t] * q2.x;
            const float gv = G[t] * q2.y;
            su += gu;
            sv += gv;
            suu = fmaf(gu, q2.x, suu);
            svv = fmaf(gv, q2.y, svv);
        }

        // Vertical accumulation into the 11 pending outputs (static slots).
        #pragma unroll
        for (int m = 0; m < 11; ++m) {
            const int s = (sl + m) % 11;
            const float gw = G[10 - m];
            acc[s][0] = fmaf(gw, su,  acc[s][0]);
            acc[s][1] = fmaf(gw, sv,  acc[s][1]);
            acc[s][2] = fmaf(gw, suu, acc[s][2]);
            acc[s][3] = fmaf(gw, svv, acc[s][3]);
        }

        // Output row o = y0 + i - 10 completes in slot sl at i >= 10.
        if (i >= 10) {
            const float mup = acc[sl][0], mum = acc[sl][1];
            const float Suu = acc[sl][2], Svv = acc[sl][3];
            const float A  = mup * mup, Bq = mum * mum;
            const float mu_sq_sum = 0.5f * (A + Bq);    // mu1^2 + mu2^2
            const float mu_cross2 = 0.5f * (A - Bq);    // 2*mu1*mu2
            const float e_sum     = 0.5f * (Suu + Svv); // Exx + Eyy
            const float e_cross2  = 0.5f * (Suu - Svv); // 2*Exy
            const float sig_sum = e_sum - mu_sq_sum;    // sig1 + sig2
            const float sig12_2 = e_cross2 - mu_cross2; // 2*sig12
            const float num = (mu_cross2 + 1e-4f) * (sig12_2 + 9e-4f) + 1e-5f;
            const float den = (mu_sq_sum + 1e-4f) * (sig_sum + 9e-4f) + 1e-5f;
            psum += __fdividef(num, den);
        }
        // Slot sl recycled: always reset.
        #pragma unroll
        for (int f = 0; f < 4; ++f) acc[sl][f] = 0.f;

        // Stage prefetched row i+1: u/v computed INLINE at the store, so the
        // first use of the loads (and the vmcnt wait) is here.
        if (notlast) {
            rowbuf[w][cur ^ 1][lane] = make_float2(pa0 + pb0, pa0 - pb0);
            if (lane < 10)
                rowbuf[w][cur ^ 1][64 + lane] = make_float2(pa1 + pb1, pa1 - pb1);
        }
        cur ^= 1;
        // Memory-only fence: DS/VMEM may not cross; VALU may.
        FENCE();
    };

    // Prologue: stage streamed row 0 (input row y0-5) into parity 0.
    loadrow(y0 - 5);
    rowbuf[w][0][lane] = make_float2(pa0 + pb0, pa0 - pb0);
    if (lane < 10) rowbuf[w][0][64 + lane] = make_float2(pa1 + pb1, pa1 - pb1);
    FENCE();

    // Main 22 rows (2 x 11 so sl stays compile-time), then 4-row tail
    // (22 % 11 == 0, so tail slot == j, still compile-time).
    for (int ii = 0; ii < 22; ii += 11) {
        #pragma unroll
        for (int j = 0; j < 11; ++j) dorow(ii + j, j);
    }
    #pragma unroll
    for (int j = 0; j < 4; ++j) dorow(22 + j, j);

    // Wave reduce -> block reduce -> ONE PLAIN STORE per block (no atomic,
    // no accumulator zeroing needed: every slot written every run).
    #pragma unroll
    for (int off = 32; off > 0; off >>= 1) psum += __shfl_xor(psum, off, 64);
    if (lane == 0) blksum[w] = psum;
    __syncthreads();
    if (tid == 0) {
        partials[d] = blksum[0] + blksum[1] + blksum[2] + blksum[3];
    }
}

__global__ __launch_bounds__(256) void ssim_final(const float* __restrict__ partials,
                                                  float* __restrict__ out) {
    __shared__ float red[4];
    const int t = threadIdx.x;
    float s = 0.f;
    #pragma unroll
    for (int k = 0; k < NBLK / 256; ++k) s += partials[t + 256 * k];
    #pragma unroll
    for (int off = 32; off > 0; off >>= 1) s += __shfl_xor(s, off, 64);
    if ((t & 63) == 0) red[t >> 6] = s;
    __syncthreads();
    if (t == 0)
        out[0] = 1.0f - (red[0] + red[1] + red[2] + red[3]) * (1.0f / 6291456.0f);
}

extern "C" void kernel_launch(void* const* d_in, const int* in_sizes, int n_in,
                              void* d_out, int out_size, void* d_ws, size_t ws_size,
                              hipStream_t stream) {
    const float* img1 = (const float*)d_in[0];
    const float* img2 = (const float*)d_in[1];
    const int*   pos  = (const int*)d_in[2];
    float* out      = (float*)d_out;
    float* partials = (float*)d_ws;      // NBLK floats = 6 KB scratch

    // No memset: every partials slot is unconditionally written by ssim_main.
    // 8 XCDs x 6 images x 32 strips; each block = 4 waves = 4 column strips.
    ssim_main<<<NBLK, 256, 0, stream>>>(img1, img2, pos, partials);
    ssim_final<<<1, 256, 0, stream>>>(partials, out);
}